// Round 4
// baseline (346.527 us; speedup 1.0000x reference)
//
#include <hip/hip_runtime.h>
#include <math.h>

#define BATCH 32768
#define LW    200
#define CIN   6
#define KSZ   5
#define FLAT  196     // LW - KSZ + 1
#define NH1   50
#define NH2   30
#define NOUT  15

// Round-10: fix the VGPR strangling with amdgpu_waves_per_eu(min,max).
// Evidence: rounds 8/9 both allocated 64-68 VGPRs (< live set) and spilled
// (round-9 WRITE_SIZE 96768 KB vs 46720 KB computable ideal -> ~50 MB scratch).
// __launch_bounds__'s 2nd arg sets only the waves-per-eu MIN; the backend
// heuristic still targets 8 waves/EU (64-VGPR budget) and spills to get
// there. Pinning max=4 gives the allocator a hard 128-VGPR budget it may
// actually use. Conv weights go to SGPRs via readfirstlane (wave-uniform),
// freeing 30 VGPRs. K2: waves_per_eu(2,4) + static-index selection of the
// eigenvector column (dynamic V[k][best] risks local-memory demotion).

// ---------------- K1 body: conv1d + fc1 partials ----------------
// NS: conv outputs/slice; TB: tile base stride (off = (NS-TB)*s, 0..3);
// NLD: float4 loads/lane/channel; TW: LDS row stride (odd); NSPLIT: slices.
template<int NS, int TB, int NLD, int TW, int NSPLIT>
__device__ __forceinline__ void conv_fc1_body(
    const float* __restrict__ x,
    const float* __restrict__ cw, const float* __restrict__ cb,
    const float* __restrict__ w1,
    float* __restrict__ part,
    float* __restrict__ tile)
{
    const int lane = threadIdx.x;
    const int bid  = blockIdx.x;
    // XCD-chunked remap: hardware round-robins XCD = bid & 7. Give XCD r the
    // batch-groups [64r, 64r+64); the NSPLIT slice-blocks of one group are
    // consecutive in q -> the 300 KB x slab is fetched once into r's L2 and
    // re-read NSPLIT-1 times as L2 hits.
    const int r = bid & 7;
    const int q = bid >> 3;               // 0 .. 64*NSPLIT-1
    const int g = r * 64 + q / NSPLIT;    // batch group (64 batches)
    const int s = q - (q / NSPLIT) * NSPLIT;

    const int kstart = NS * s;            // conv-output slice [kstart, kstart+NS)
    const int tbase  = TB * s;            // 16B-aligned tile base col
    const int off    = kstart - tbase;    // window offset in tile (0..3)

    // conv weights / bias: wave-uniform -> pin to SGPRs (frees 31 VGPRs)
    float w[CIN][KSZ];
#pragma unroll
    for (int c = 0; c < CIN; ++c)
#pragma unroll
        for (int k = 0; k < KSZ; ++k)
            w[c][k] = __int_as_float(
                __builtin_amdgcn_readfirstlane(__float_as_int(cw[c * KSZ + k])));
    const float bias = __int_as_float(
        __builtin_amdgcn_readfirstlane(__float_as_int(cb[0])));

    // staging descriptors: float4 #g4 = lane + 64u of the [64 rows][NLD f4] tile
    int goff[NLD];
    int loff[NLD];
#pragma unroll
    for (int u = 0; u < NLD; ++u) {
        int g4  = lane + 64 * u;
        int row = g4 / NLD;               // pow2 or magic-div (compile-time)
        int c4  = g4 - row * NLD;
        goff[u] = row * (CIN * LW) + 4 * c4;
        loff[u] = row * TW + 4 * c4;
    }
    const float* xw = x + (size_t)g * 64 * (CIN * LW) + tbase;

    float acc[NS];
#pragma unroll
    for (int i = 0; i < NS; ++i) acc[i] = bias;

    // prologue: issue channel 0 loads (NLD independent dwordx4)
    float4 buf[NLD];
#pragma unroll
    for (int u = 0; u < NLD; ++u)
        buf[u] = *(const float4*)(xw + goff[u]);

#pragma unroll
    for (int ch = 0; ch < CIN; ++ch) {
        // drain buf -> LDS (wave-internal, in-order; no barrier needed)
#pragma unroll
        for (int u = 0; u < NLD; ++u) {
            float* dst = tile + loff[u];
            dst[0] = buf[u].x; dst[1] = buf[u].y; dst[2] = buf[u].z; dst[3] = buf[u].w;
        }
        // issue next channel's loads before consuming this one (hide latency)
        if (ch + 1 < CIN) {
#pragma unroll
            for (int u = 0; u < NLD; ++u)
                buf[u] = *(const float4*)(xw + (ch + 1) * LW + goff[u]);
        }
        // conv accumulate (batch = lane); odd TW -> conflict-free
        const float* row = tile + lane * TW + off;
        float x0 = row[0], x1 = row[1], x2 = row[2], x3 = row[3];
#pragma unroll
        for (int i = 0; i < NS; ++i) {
            float x4v = row[i + 4];
            float a = acc[i];
            a = fmaf(x0, w[ch][0], a);
            a = fmaf(x1, w[ch][1], a);
            a = fmaf(x2, w[ch][2], a);
            a = fmaf(x3, w[ch][3], a);
            a = fmaf(x4v, w[ch][4], a);
            acc[i] = a;
            x0 = x1; x1 = x2; x2 = x3; x3 = x4v;
        }
    }

    // fc1 partials: rows kstart..kstart+NS-1 of w1 (wave-uniform -> s_load)
    float h1p[NH1];
#pragma unroll
    for (int j = 0; j < NH1; ++j) h1p[j] = 0.f;
#pragma unroll
    for (int ii = 0; ii < NS; ++ii) {
        const float* wrow = w1 + (size_t)(kstart + ii) * NH1;
        float c = acc[ii];
#pragma unroll
        for (int j = 0; j < NH1; ++j) h1p[j] = fmaf(c, wrow[j], h1p[j]);
    }

    // store partials: part[(s*NH1 + j)*BATCH + b] -- lane-contiguous (coalesced)
    float* pb = part + (size_t)(s * NH1) * BATCH + (size_t)g * 64 + lane;
#pragma unroll
    for (int j = 0; j < NH1; ++j)
        pb[(size_t)j * BATCH] = h1p[j];
}

// Primary path: 7-way split. waves_per_eu(4,4) -> hard 128-VGPR budget, no
// occupancy-chasing reallocation. Peak live ~115 (conv) / ~85 (fc1) < 128.
__global__ void __launch_bounds__(64) __attribute__((amdgpu_waves_per_eu(4, 4)))
conv_fc1_k7(const float* __restrict__ x,
            const float* __restrict__ cw, const float* __restrict__ cb,
            const float* __restrict__ w1, float* __restrict__ part)
{
    __shared__ float tile[64 * 33];
    conv_fc1_body<28, 28, 8, 33, 7>(x, cw, cb, w1, part, tile);
}

// Fallbacks (smaller workspace): live sets are larger, so lower wave targets.
__global__ void __launch_bounds__(64) __attribute__((amdgpu_waves_per_eu(2, 2)))
conv_fc1_k4(const float* __restrict__ x,
            const float* __restrict__ cw, const float* __restrict__ cb,
            const float* __restrict__ w1, float* __restrict__ part)
{
    __shared__ float tile[64 * 57];
    conv_fc1_body<49, 48, 14, 57, 4>(x, cw, cb, w1, part, tile);
}

__global__ void __launch_bounds__(64) __attribute__((amdgpu_waves_per_eu(1, 1)))
conv_fc1_k2(const float* __restrict__ x,
            const float* __restrict__ cw, const float* __restrict__ cb,
            const float* __restrict__ w1, float* __restrict__ part)
{
    __shared__ float tile[64 * 105];
    conv_fc1_body<98, 96, 26, 105, 2>(x, cw, cb, w1, part, tile);
}

// ---------------- K2: reduce + fc2 + fc3 + Procrustes ----------------
template<int NSPLIT>
__global__ void __launch_bounds__(64) __attribute__((amdgpu_waves_per_eu(2, 4)))
tail_kernel(
    const float* __restrict__ part,
    const float* __restrict__ b1,
    const float* __restrict__ w2, const float* __restrict__ b2,
    const float* __restrict__ w3, const float* __restrict__ b3,
    float* __restrict__ out)
{
    const int bid = blockIdx.x;
    const int g   = (bid & 7) * 64 + (bid >> 3);   // same XCD chunking as K1
    const int b   = g * 64 + threadIdx.x;

    // h1 = relu(b1 + sum_s partial_s)   (coalesced loads across lanes)
    float h1[NH1];
#pragma unroll
    for (int j = 0; j < NH1; ++j) {
        float a = b1[j];
#pragma unroll
        for (int s = 0; s < NSPLIT; ++s)
            a += part[(size_t)(s * NH1 + j) * BATCH + b];
        h1[j] = fmaxf(a, 0.f);
    }

    // fc2
    float h2[NH2];
#pragma unroll
    for (int j = 0; j < NH2; ++j) h2[j] = b2[j];
#pragma unroll
    for (int k = 0; k < NH1; ++k) {
        float hk = h1[k];
        const float* row = w2 + k * NH2;              // uniform -> s_load
#pragma unroll
        for (int j = 0; j < NH2; ++j) h2[j] = fmaf(hk, row[j], h2[j]);
    }
#pragma unroll
    for (int j = 0; j < NH2; ++j) h2[j] = fmaxf(h2[j], 0.f);

    // fc3 (no relu)
    float o[NOUT];
#pragma unroll
    for (int j = 0; j < NOUT; ++j) o[j] = b3[j];
#pragma unroll
    for (int k = 0; k < NH2; ++k) {
        float hk = h2[k];
        const float* row = w3 + k * NOUT;             // uniform -> s_load
#pragma unroll
        for (int j = 0; j < NOUT; ++j) o[j] = fmaf(hk, row[j], o[j]);
    }

    // ---- closest proper rotation (Davenport K-matrix, f32 Jacobi) ----
    float r00 = o[0], r01 = o[1], r02 = o[2];
    float r10 = o[3], r11 = o[4], r12 = o[5];
    float r20 = o[6], r21 = o[7], r22 = o[8];

    float A[4][4], V[4][4];
    A[0][0] = r00 + r11 + r22;
    A[1][1] = r00 - r11 - r22;
    A[2][2] = r11 - r00 - r22;
    A[3][3] = r22 - r00 - r11;
    A[0][1] = A[1][0] = r21 - r12;
    A[0][2] = A[2][0] = r02 - r20;
    A[0][3] = A[3][0] = r10 - r01;
    A[1][2] = A[2][1] = r01 + r10;
    A[1][3] = A[3][1] = r02 + r20;
    A[2][3] = A[3][2] = r12 + r21;
#pragma unroll
    for (int i = 0; i < 4; ++i)
#pragma unroll
        for (int j = 0; j < 4; ++j) V[i][j] = (i == j) ? 1.f : 0.f;

    const int pr[6][2] = {{0,1},{0,2},{0,3},{1,2},{1,3},{2,3}};
    for (int sweep = 0; sweep < 7; ++sweep) {
#pragma unroll
        for (int pi = 0; pi < 6; ++pi) {
            const int p = pr[pi][0], qq = pr[pi][1];
            float apq = A[p][qq];
            if (fabsf(apq) > 1e-20f) {
                float theta = (A[qq][qq] - A[p][p]) / (2.f * apq);
                float t = copysignf(1.f, theta) / (fabsf(theta) + sqrtf(1.f + theta * theta));
                float c = rsqrtf(1.f + t * t);
                float sn = t * c;
#pragma unroll
                for (int k = 0; k < 4; ++k) {
                    float akp = A[k][p], akq = A[k][qq];
                    A[k][p] = c * akp - sn * akq;
                    A[k][qq] = sn * akp + c * akq;
                }
#pragma unroll
                for (int k = 0; k < 4; ++k) {
                    float apk = A[p][k], aqk = A[qq][k];
                    A[p][k] = c * apk - sn * aqk;
                    A[qq][k] = sn * apk + c * aqk;
                }
#pragma unroll
                for (int k = 0; k < 4; ++k) {
                    float vkp = V[k][p], vkq = V[k][qq];
                    V[k][p] = c * vkp - sn * vkq;
                    V[k][qq] = sn * vkp + c * vkq;
                }
            }
        }
    }

    int best = 0;
    float bl = A[0][0];
#pragma unroll
    for (int i = 1; i < 4; ++i)
        if (A[i][i] > bl) { bl = A[i][i]; best = i; }

    // static-index column select (dynamic V[k][best] risks scratch demotion)
    float vsel[4];
#pragma unroll
    for (int k = 0; k < 4; ++k) {
        float v = V[k][0];
        v = (best == 1) ? V[k][1] : v;
        v = (best == 2) ? V[k][2] : v;
        v = (best == 3) ? V[k][3] : v;
        vsel[k] = v;
    }
    float vw = vsel[0], vx = vsel[1], vy = vsel[2], vz = vsel[3];
    float inv = rsqrtf(vw * vw + vx * vx + vy * vy + vz * vz);
    vw *= inv; vx *= inv; vy *= inv; vz *= inv;

    float xx = vx * vx, yy = vy * vy, zz = vz * vz;
    float xy = vx * vy, xz = vx * vz, yz = vy * vz;
    float wx = vw * vx, wy = vw * vy, wz = vw * vz;

    float* ob = out + (long)b * NOUT;
    ob[0]  = 1.f - 2.f * (yy + zz);
    ob[1]  = 2.f * (xy - wz);
    ob[2]  = 2.f * (xz + wy);
    ob[3]  = 2.f * (xy + wz);
    ob[4]  = 1.f - 2.f * (xx + zz);
    ob[5]  = 2.f * (yz - wx);
    ob[6]  = 2.f * (xz - wy);
    ob[7]  = 2.f * (yz + wx);
    ob[8]  = 1.f - 2.f * (xx + yy);
    ob[9]  = o[9];
    ob[10] = o[10];
    ob[11] = o[11];
    ob[12] = o[12];
    ob[13] = o[13];
    ob[14] = o[14];
}

extern "C" void kernel_launch(void* const* d_in, const int* in_sizes, int n_in,
                              void* d_out, int out_size, void* d_ws, size_t ws_size,
                              hipStream_t stream) {
    const float* x  = (const float*)d_in[0];
    const float* cw = (const float*)d_in[1];
    const float* cb = (const float*)d_in[2];
    const float* w1 = (const float*)d_in[3];
    const float* b1 = (const float*)d_in[4];
    const float* w2 = (const float*)d_in[5];
    const float* b2 = (const float*)d_in[6];
    const float* w3 = (const float*)d_in[7];
    const float* b3 = (const float*)d_in[8];
    float* outp = (float*)d_out;
    float* part = (float*)d_ws;

    const size_t need7 = (size_t)7 * NH1 * BATCH * sizeof(float);  // 45.9 MB
    const size_t need4 = (size_t)4 * NH1 * BATCH * sizeof(float);  // 26.2 MB

    if (ws_size >= need7) {
        conv_fc1_k7<<<7 * (BATCH / 64), 64, 0, stream>>>(x, cw, cb, w1, part);
        tail_kernel<7><<<BATCH / 64, 64, 0, stream>>>(part, b1, w2, b2, w3, b3, outp);
    } else if (ws_size >= need4) {
        conv_fc1_k4<<<4 * (BATCH / 64), 64, 0, stream>>>(x, cw, cb, w1, part);
        tail_kernel<4><<<BATCH / 64, 64, 0, stream>>>(part, b1, w2, b2, w3, b3, outp);
    } else {
        conv_fc1_k2<<<2 * (BATCH / 64), 64, 0, stream>>>(x, cw, cb, w1, part);
        tail_kernel<2><<<BATCH / 64, 64, 0, stream>>>(part, b1, w2, b2, w3, b3, outp);
    }
}

// Round 5
// 331.367 us; speedup vs baseline: 1.0457x; 1.0457x over previous
//
#include <hip/hip_runtime.h>
#include <math.h>

#define BATCH 32768
#define LW    200
#define CIN   6
#define KSZ   5
#define FLAT  196     // LW - KSZ + 1
#define NH1   50
#define NH2   30
#define NOUT  15
#define XROW  (CIN * LW)   // 1200 floats per batch row

// Round-11: REGISTER DIET -- fit every phase in 64 VGPRs instead of fighting
// the allocator (rounds 8-10: launch_bounds min and waves_per_eu(4,4) both
// ignored; VGPR pinned at 64, ~50 MB/dispatch scratch: WRITE 96768 KB vs
// 44800 ideal). Diets:
//  (1) half-staging: buf[4] float4 (32 rows/turn), 2nd half addr = 1st+const
//      -> conv live ~60;
//  (2) two-pass fc1 (25+25 cols over acc[28]) -> fc1 live ~58;
//  (3) K2 fuses reduce+relu+fc2 per-k (no h1[50] array) -> live ~45.
// Spill signature to verify: K1 WRITE_SIZE == 44800 KB (partials only).

// ---------------- K1 primary: 7-way split, NS=28, TW=33 ----------------
__global__ void __launch_bounds__(64)
conv_fc1_k7(const float* __restrict__ x,
            const float* __restrict__ cw, const float* __restrict__ cb,
            const float* __restrict__ w1, float* __restrict__ part)
{
    __shared__ float tile[64 * 33];       // 8448 B

    const int lane = threadIdx.x;
    const int bid  = blockIdx.x;
    // XCD-chunked remap: HW round-robins XCD = bid & 7; give XCD r the batch
    // groups [64r,64r+64) so all 7 slice-blocks of a group share r's L2.
    const int r  = bid & 7;
    const int q  = bid >> 3;              // 0 .. 64*7-1
    const int gq = q / 7;
    const int s  = q - gq * 7;            // slice 0..6
    const int g  = r * 64 + gq;           // batch group (64 batches)
    const int kstart = 28 * s;            // conv-output slice & tile base col

    // conv weights / bias: wave-uniform -> SGPRs
    float w[CIN][KSZ];
#pragma unroll
    for (int c = 0; c < CIN; ++c)
#pragma unroll
        for (int k = 0; k < KSZ; ++k)
            w[c][k] = __int_as_float(
                __builtin_amdgcn_readfirstlane(__float_as_int(cw[c * KSZ + k])));
    const float bias = __int_as_float(
        __builtin_amdgcn_readfirstlane(__float_as_int(cb[0])));

    // half-tile staging descriptors (rows 0..31): float4 #g4 = lane + 64u.
    // Second half (rows 32..63) = same + 32*XROW (global) / + 32*33 (LDS).
    int goff[4];
    int loff[4];
#pragma unroll
    for (int u = 0; u < 4; ++u) {
        int g4  = lane + 64 * u;
        int row = g4 >> 3;                // 8 f4 per row
        int c4  = g4 & 7;
        goff[u] = row * XROW + 4 * c4;
        loff[u] = row * 33 + 4 * c4;      // TW=33 odd -> conflict-free reads
    }
    const float* xw = x + (size_t)g * 64 * XROW + kstart;

    float acc[28];
#pragma unroll
    for (int i = 0; i < 28; ++i) acc[i] = bias;

    // prologue: half A of channel 0
    float4 buf[4];
#pragma unroll
    for (int u = 0; u < 4; ++u)
        buf[u] = *(const float4*)(xw + goff[u]);

#pragma unroll
    for (int ch = 0; ch < CIN; ++ch) {
        // drain half A (rows 0..31)
#pragma unroll
        for (int u = 0; u < 4; ++u) {
            float* dst = tile + loff[u];
            dst[0] = buf[u].x; dst[1] = buf[u].y; dst[2] = buf[u].z; dst[3] = buf[u].w;
        }
        // issue half B (rows 32..63) of this channel
#pragma unroll
        for (int u = 0; u < 4; ++u)
            buf[u] = *(const float4*)(xw + ch * LW + 32 * XROW + goff[u]);
        // drain half B
#pragma unroll
        for (int u = 0; u < 4; ++u) {
            float* dst = tile + 32 * 33 + loff[u];
            dst[0] = buf[u].x; dst[1] = buf[u].y; dst[2] = buf[u].z; dst[3] = buf[u].w;
        }
        // issue half A of next channel; its latency hides under conv(ch)
        if (ch + 1 < CIN) {
#pragma unroll
            for (int u = 0; u < 4; ++u)
                buf[u] = *(const float4*)(xw + (ch + 1) * LW + goff[u]);
        }
        // conv accumulate (batch = lane)
        const float* row = tile + lane * 33;
        float x0 = row[0], x1 = row[1], x2 = row[2], x3 = row[3];
#pragma unroll
        for (int i = 0; i < 28; ++i) {
            float x4v = row[i + 4];
            float a = acc[i];
            a = fmaf(x0, w[ch][0], a);
            a = fmaf(x1, w[ch][1], a);
            a = fmaf(x2, w[ch][2], a);
            a = fmaf(x3, w[ch][3], a);
            a = fmaf(x4v, w[ch][4], a);
            acc[i] = a;
            x0 = x1; x1 = x2; x2 = x3; x3 = x4v;
        }
    }

    // ---- fc1 partials, TWO PASSES of 25 columns (live: acc[28]+h1p[25]) ----
    float* pb = part + (size_t)(s * NH1) * BATCH + (size_t)g * 64 + lane;
#pragma unroll
    for (int half = 0; half < 2; ++half) {
        const int j0 = half * 25;
        float h1p[25];
#pragma unroll
        for (int j = 0; j < 25; ++j) h1p[j] = 0.f;
#pragma unroll
        for (int ii = 0; ii < 28; ++ii) {
            const float* wrow = w1 + (size_t)(kstart + ii) * NH1 + j0;  // uniform -> s_load
            float c = acc[ii];
#pragma unroll
            for (int j = 0; j < 25; ++j) h1p[j] = fmaf(c, wrow[j], h1p[j]);
        }
        // store partials: part[(s*NH1 + j0+j)*BATCH + b] (lane-coalesced)
#pragma unroll
        for (int j = 0; j < 25; ++j)
            pb[(size_t)(j0 + j) * BATCH] = h1p[j];
    }
}

// ---------------- K1 fallbacks (smaller workspace; round-9 generic body) ----
template<int NS, int TB, int NLD, int TW, int NSPLIT>
__device__ __forceinline__ void conv_fc1_body(
    const float* __restrict__ x,
    const float* __restrict__ cw, const float* __restrict__ cb,
    const float* __restrict__ w1, float* __restrict__ part,
    float* __restrict__ tile)
{
    const int lane = threadIdx.x;
    const int bid  = blockIdx.x;
    const int r = bid & 7;
    const int q = bid >> 3;
    const int g = r * 64 + q / NSPLIT;
    const int s = q - (q / NSPLIT) * NSPLIT;
    const int kstart = NS * s;
    const int tbase  = TB * s;
    const int off    = kstart - tbase;

    float w[CIN][KSZ];
#pragma unroll
    for (int c = 0; c < CIN; ++c)
#pragma unroll
        for (int k = 0; k < KSZ; ++k)
            w[c][k] = __int_as_float(
                __builtin_amdgcn_readfirstlane(__float_as_int(cw[c * KSZ + k])));
    const float bias = __int_as_float(
        __builtin_amdgcn_readfirstlane(__float_as_int(cb[0])));

    int goff[NLD], loff[NLD];
#pragma unroll
    for (int u = 0; u < NLD; ++u) {
        int g4  = lane + 64 * u;
        int row = g4 / NLD;
        int c4  = g4 - row * NLD;
        goff[u] = row * XROW + 4 * c4;
        loff[u] = row * TW + 4 * c4;
    }
    const float* xw = x + (size_t)g * 64 * XROW + tbase;

    float acc[NS];
#pragma unroll
    for (int i = 0; i < NS; ++i) acc[i] = bias;

    float4 buf[NLD];
#pragma unroll
    for (int u = 0; u < NLD; ++u) buf[u] = *(const float4*)(xw + goff[u]);

#pragma unroll
    for (int ch = 0; ch < CIN; ++ch) {
#pragma unroll
        for (int u = 0; u < NLD; ++u) {
            float* dst = tile + loff[u];
            dst[0] = buf[u].x; dst[1] = buf[u].y; dst[2] = buf[u].z; dst[3] = buf[u].w;
        }
        if (ch + 1 < CIN) {
#pragma unroll
            for (int u = 0; u < NLD; ++u)
                buf[u] = *(const float4*)(xw + (ch + 1) * LW + goff[u]);
        }
        const float* row = tile + lane * TW + off;
        float x0 = row[0], x1 = row[1], x2 = row[2], x3 = row[3];
#pragma unroll
        for (int i = 0; i < NS; ++i) {
            float x4v = row[i + 4];
            float a = acc[i];
            a = fmaf(x0, w[ch][0], a);
            a = fmaf(x1, w[ch][1], a);
            a = fmaf(x2, w[ch][2], a);
            a = fmaf(x3, w[ch][3], a);
            a = fmaf(x4v, w[ch][4], a);
            acc[i] = a;
            x0 = x1; x1 = x2; x2 = x3; x3 = x4v;
        }
    }

    float* pb = part + (size_t)(s * NH1) * BATCH + (size_t)g * 64 + lane;
#pragma unroll
    for (int half = 0; half < 2; ++half) {
        const int j0 = half * 25;
        float h1p[25];
#pragma unroll
        for (int j = 0; j < 25; ++j) h1p[j] = 0.f;
#pragma unroll
        for (int ii = 0; ii < NS; ++ii) {
            const float* wrow = w1 + (size_t)(kstart + ii) * NH1 + j0;
            float c = acc[ii];
#pragma unroll
            for (int j = 0; j < 25; ++j) h1p[j] = fmaf(c, wrow[j], h1p[j]);
        }
#pragma unroll
        for (int j = 0; j < 25; ++j)
            pb[(size_t)(j0 + j) * BATCH] = h1p[j];
    }
}

__global__ void __launch_bounds__(64)
conv_fc1_k4(const float* __restrict__ x,
            const float* __restrict__ cw, const float* __restrict__ cb,
            const float* __restrict__ w1, float* __restrict__ part)
{
    __shared__ float tile[64 * 57];
    conv_fc1_body<49, 48, 14, 57, 4>(x, cw, cb, w1, part, tile);
}

__global__ void __launch_bounds__(64)
conv_fc1_k2(const float* __restrict__ x,
            const float* __restrict__ cw, const float* __restrict__ cb,
            const float* __restrict__ w1, float* __restrict__ part)
{
    __shared__ float tile[64 * 105];
    conv_fc1_body<98, 96, 26, 105, 2>(x, cw, cb, w1, part, tile);
}

// ---------------- K2: fused reduce+fc2, fc3, Procrustes ----------------
// No h1[50] array: per k, h1[k] = relu(b1[k] + sum_s part) is consumed
// immediately into h2[30]. Peak live ~45 VGPRs -> no spill at 64.
template<int NSPLIT>
__global__ void __launch_bounds__(64)
tail_kernel(
    const float* __restrict__ part,
    const float* __restrict__ b1,
    const float* __restrict__ w2, const float* __restrict__ b2,
    const float* __restrict__ w3, const float* __restrict__ b3,
    float* __restrict__ out)
{
    const int bid = blockIdx.x;
    const int g   = (bid & 7) * 64 + (bid >> 3);   // same XCD chunking as K1
    const int b   = g * 64 + threadIdx.x;
    const float* pb = part + b;

    float h2[NH2];
#pragma unroll
    for (int j = 0; j < NH2; ++j) h2[j] = b2[j];

#pragma unroll
    for (int k = 0; k < NH1; ++k) {
        float a = b1[k];                           // uniform -> s_load
#pragma unroll
        for (int s = 0; s < NSPLIT; ++s)
            a += pb[(size_t)(s * NH1 + k) * BATCH];
        float hk = fmaxf(a, 0.f);
        const float* row = w2 + k * NH2;           // uniform -> s_load
#pragma unroll
        for (int j = 0; j < NH2; ++j) h2[j] = fmaf(hk, row[j], h2[j]);
    }
#pragma unroll
    for (int j = 0; j < NH2; ++j) h2[j] = fmaxf(h2[j], 0.f);

    // fc3 (no relu)
    float o[NOUT];
#pragma unroll
    for (int j = 0; j < NOUT; ++j) o[j] = b3[j];
#pragma unroll
    for (int k = 0; k < NH2; ++k) {
        float hk = h2[k];
        const float* row = w3 + k * NOUT;          // uniform -> s_load
#pragma unroll
        for (int j = 0; j < NOUT; ++j) o[j] = fmaf(hk, row[j], o[j]);
    }

    // ---- closest proper rotation (Davenport K-matrix, f32 Jacobi) ----
    float r00 = o[0], r01 = o[1], r02 = o[2];
    float r10 = o[3], r11 = o[4], r12 = o[5];
    float r20 = o[6], r21 = o[7], r22 = o[8];

    float A[4][4], V[4][4];
    A[0][0] = r00 + r11 + r22;
    A[1][1] = r00 - r11 - r22;
    A[2][2] = r11 - r00 - r22;
    A[3][3] = r22 - r00 - r11;
    A[0][1] = A[1][0] = r21 - r12;
    A[0][2] = A[2][0] = r02 - r20;
    A[0][3] = A[3][0] = r10 - r01;
    A[1][2] = A[2][1] = r01 + r10;
    A[1][3] = A[3][1] = r02 + r20;
    A[2][3] = A[3][2] = r12 + r21;
#pragma unroll
    for (int i = 0; i < 4; ++i)
#pragma unroll
        for (int j = 0; j < 4; ++j) V[i][j] = (i == j) ? 1.f : 0.f;

    const int pr[6][2] = {{0,1},{0,2},{0,3},{1,2},{1,3},{2,3}};
    for (int sweep = 0; sweep < 7; ++sweep) {
#pragma unroll
        for (int pi = 0; pi < 6; ++pi) {
            const int p = pr[pi][0], qq = pr[pi][1];
            float apq = A[p][qq];
            if (fabsf(apq) > 1e-20f) {
                float theta = (A[qq][qq] - A[p][p]) / (2.f * apq);
                float t = copysignf(1.f, theta) / (fabsf(theta) + sqrtf(1.f + theta * theta));
                float c = rsqrtf(1.f + t * t);
                float sn = t * c;
#pragma unroll
                for (int k = 0; k < 4; ++k) {
                    float akp = A[k][p], akq = A[k][qq];
                    A[k][p] = c * akp - sn * akq;
                    A[k][qq] = sn * akp + c * akq;
                }
#pragma unroll
                for (int k = 0; k < 4; ++k) {
                    float apk = A[p][k], aqk = A[qq][k];
                    A[p][k] = c * apk - sn * aqk;
                    A[qq][k] = sn * apk + c * aqk;
                }
#pragma unroll
                for (int k = 0; k < 4; ++k) {
                    float vkp = V[k][p], vkq = V[k][qq];
                    V[k][p] = c * vkp - sn * vkq;
                    V[k][qq] = sn * vkp + c * vkq;
                }
            }
        }
    }

    int best = 0;
    float bl = A[0][0];
#pragma unroll
    for (int i = 1; i < 4; ++i)
        if (A[i][i] > bl) { bl = A[i][i]; best = i; }

    // static-index column select (dynamic V[k][best] risks scratch demotion)
    float vsel[4];
#pragma unroll
    for (int k = 0; k < 4; ++k) {
        float v = V[k][0];
        v = (best == 1) ? V[k][1] : v;
        v = (best == 2) ? V[k][2] : v;
        v = (best == 3) ? V[k][3] : v;
        vsel[k] = v;
    }
    float vw = vsel[0], vx = vsel[1], vy = vsel[2], vz = vsel[3];
    float inv = rsqrtf(vw * vw + vx * vx + vy * vy + vz * vz);
    vw *= inv; vx *= inv; vy *= inv; vz *= inv;

    float xx = vx * vx, yy = vy * vy, zz = vz * vz;
    float xy = vx * vy, xz = vx * vz, yz = vy * vz;
    float wx = vw * vx, wy = vw * vy, wz = vw * vz;

    float* ob = out + (long)b * NOUT;
    ob[0]  = 1.f - 2.f * (yy + zz);
    ob[1]  = 2.f * (xy - wz);
    ob[2]  = 2.f * (xz + wy);
    ob[3]  = 2.f * (xy + wz);
    ob[4]  = 1.f - 2.f * (xx + zz);
    ob[5]  = 2.f * (yz - wx);
    ob[6]  = 2.f * (xz - wy);
    ob[7]  = 2.f * (yz + wx);
    ob[8]  = 1.f - 2.f * (xx + yy);
    ob[9]  = o[9];
    ob[10] = o[10];
    ob[11] = o[11];
    ob[12] = o[12];
    ob[13] = o[13];
    ob[14] = o[14];
}

extern "C" void kernel_launch(void* const* d_in, const int* in_sizes, int n_in,
                              void* d_out, int out_size, void* d_ws, size_t ws_size,
                              hipStream_t stream) {
    const float* x  = (const float*)d_in[0];
    const float* cw = (const float*)d_in[1];
    const float* cb = (const float*)d_in[2];
    const float* w1 = (const float*)d_in[3];
    const float* b1 = (const float*)d_in[4];
    const float* w2 = (const float*)d_in[5];
    const float* b2 = (const float*)d_in[6];
    const float* w3 = (const float*)d_in[7];
    const float* b3 = (const float*)d_in[8];
    float* outp = (float*)d_out;
    float* part = (float*)d_ws;

    const size_t need7 = (size_t)7 * NH1 * BATCH * sizeof(float);  // 45.9 MB
    const size_t need4 = (size_t)4 * NH1 * BATCH * sizeof(float);  // 26.2 MB

    if (ws_size >= need7) {
        conv_fc1_k7<<<7 * (BATCH / 64), 64, 0, stream>>>(x, cw, cb, w1, part);
        tail_kernel<7><<<BATCH / 64, 64, 0, stream>>>(part, b1, w2, b2, w3, b3, outp);
    } else if (ws_size >= need4) {
        conv_fc1_k4<<<4 * (BATCH / 64), 64, 0, stream>>>(x, cw, cb, w1, part);
        tail_kernel<4><<<BATCH / 64, 64, 0, stream>>>(part, b1, w2, b2, w3, b3, outp);
    } else {
        conv_fc1_k2<<<2 * (BATCH / 64), 64, 0, stream>>>(x, cw, cb, w1, part);
        tail_kernel<2><<<BATCH / 64, 64, 0, stream>>>(part, b1, w2, b2, w3, b3, outp);
    }
}

// Round 6
// 329.013 us; speedup vs baseline: 1.0532x; 1.0072x over previous
//
#include <hip/hip_runtime.h>
#include <math.h>

#define BATCH 32768
#define LW    200
#define CIN   6
#define KSZ   5
#define FLAT  196     // LW - KSZ + 1
#define NH1   50
#define NH2   30
#define NOUT  15
#define XROW  (CIN * LW)   // 1200 floats per batch row

// Round-12: DELETE THE LDS TILE. Rounds 9-11 showed K1 latency-bound
// (VALUBusy <=18%) with the serial chains being self-inflicted: half-B
// drain waits (6x full load latency), LDS write->read round-trips, and
// fc1's per-row s_load chain. New conv: per-lane DIRECT register window --
// each lane (= one batch row) loads its 32-float window (8x dwordx4,
// 1-2 cache lines; 64 lanes x 2 lines = 16 KB fits 32 KB L1) double-
// buffered one channel ahead. Zero LDS, zero ds ops, all loads independent.
// All window indices compile-time constant (no scratch demotion).
// fc1: two 25-col passes with 2-row pairing (halves s_load stall count).
// Spill watch: VGPR must stay >=100 (64 => allocator strangled again).

__device__ __forceinline__ float fget(const float4 (&a)[8], int i) {
    // i is compile-time constant under full unroll -> folds to a register ref
    const float4 v = a[i >> 2];
    const int m = i & 3;
    return m == 0 ? v.x : (m == 1 ? v.y : (m == 2 ? v.z : v.w));
}

// ---------------- K1 primary: 7-way split, NS=28, no LDS ----------------
__global__ void __launch_bounds__(64)
conv_fc1_k7(const float* __restrict__ x,
            const float* __restrict__ cw, const float* __restrict__ cb,
            const float* __restrict__ w1, float* __restrict__ part)
{
    const int lane = threadIdx.x;
    const int bid  = blockIdx.x;
    // XCD-chunked remap: HW round-robins XCD = bid & 7; give XCD r the batch
    // groups [64r,64r+64) so all 7 slice-blocks of a group share r's L2.
    const int r  = bid & 7;
    const int q  = bid >> 3;              // 0 .. 64*7-1
    const int gq = q / 7;
    const int s  = q - gq * 7;            // slice 0..6
    const int g  = r * 64 + gq;           // batch group (64 batches)
    const int kstart = 28 * s;            // conv-output slice base (28s: f4-aligned)

    // conv weights / bias: wave-uniform -> SGPRs
    float w[CIN][KSZ];
#pragma unroll
    for (int c = 0; c < CIN; ++c)
#pragma unroll
        for (int k = 0; k < KSZ; ++k)
            w[c][k] = __int_as_float(
                __builtin_amdgcn_readfirstlane(__float_as_int(cw[c * KSZ + k])));
    const float bias = __int_as_float(
        __builtin_amdgcn_readfirstlane(__float_as_int(cb[0])));

    // per-lane row base: this lane's batch, window cols [kstart, kstart+32)
    const float* xb = x + (size_t)(g * 64 + lane) * XROW + kstart;

    float acc[28];
#pragma unroll
    for (int i = 0; i < 28; ++i) acc[i] = bias;

    float4 A[8], B[8];
    // prologue: channel 0 window (8 independent dwordx4, per-lane)
#pragma unroll
    for (int u = 0; u < 8; ++u)
        A[u] = *(const float4*)(xb + 4 * u);

#pragma unroll
    for (int ch = 0; ch < CIN; ch += 2) {
        // issue ch+1 before consuming ch (its latency hides under 140 FMA)
#pragma unroll
        for (int u = 0; u < 8; ++u)
            B[u] = *(const float4*)(xb + (ch + 1) * LW + 4 * u);
        // conv channel ch from registers (static indices only)
#pragma unroll
        for (int i = 0; i < 28; ++i) {
            float a = acc[i];
            a = fmaf(fget(A, i + 0), w[ch][0], a);
            a = fmaf(fget(A, i + 1), w[ch][1], a);
            a = fmaf(fget(A, i + 2), w[ch][2], a);
            a = fmaf(fget(A, i + 3), w[ch][3], a);
            a = fmaf(fget(A, i + 4), w[ch][4], a);
            acc[i] = a;
        }
        if (ch + 2 < CIN) {
#pragma unroll
            for (int u = 0; u < 8; ++u)
                A[u] = *(const float4*)(xb + (ch + 2) * LW + 4 * u);
        }
        // conv channel ch+1
#pragma unroll
        for (int i = 0; i < 28; ++i) {
            float a = acc[i];
            a = fmaf(fget(B, i + 0), w[ch + 1][0], a);
            a = fmaf(fget(B, i + 1), w[ch + 1][1], a);
            a = fmaf(fget(B, i + 2), w[ch + 1][2], a);
            a = fmaf(fget(B, i + 3), w[ch + 1][3], a);
            a = fmaf(fget(B, i + 4), w[ch + 1][4], a);
            acc[i] = a;
        }
    }

    // ---- fc1 partials: two 25-col passes, 2-row pairing ----
    float* pb = part + (size_t)(s * NH1) * BATCH + (size_t)g * 64 + lane;
#pragma unroll
    for (int half = 0; half < 2; ++half) {
        const int j0 = half * 25;
        float h1p[25];
#pragma unroll
        for (int j = 0; j < 25; ++j) h1p[j] = 0.f;
#pragma unroll
        for (int ii = 0; ii < 28; ii += 2) {
            const float* wr0 = w1 + (size_t)(kstart + ii) * NH1 + j0;  // uniform -> s_load
            const float* wr1 = wr0 + NH1;
            float c0 = acc[ii], c1 = acc[ii + 1];
#pragma unroll
            for (int j = 0; j < 25; ++j)
                h1p[j] = fmaf(c1, wr1[j], fmaf(c0, wr0[j], h1p[j]));
        }
#pragma unroll
        for (int j = 0; j < 25; ++j)
            pb[(size_t)(j0 + j) * BATCH] = h1p[j];
    }
}

// ---------------- K1 fallbacks (smaller workspace; round-11 LDS body) ----
template<int NS, int TB, int NLD, int TW, int NSPLIT>
__device__ __forceinline__ void conv_fc1_body(
    const float* __restrict__ x,
    const float* __restrict__ cw, const float* __restrict__ cb,
    const float* __restrict__ w1, float* __restrict__ part,
    float* __restrict__ tile)
{
    const int lane = threadIdx.x;
    const int bid  = blockIdx.x;
    const int r = bid & 7;
    const int q = bid >> 3;
    const int g = r * 64 + q / NSPLIT;
    const int s = q - (q / NSPLIT) * NSPLIT;
    const int kstart = NS * s;
    const int tbase  = TB * s;
    const int off    = kstart - tbase;

    float w[CIN][KSZ];
#pragma unroll
    for (int c = 0; c < CIN; ++c)
#pragma unroll
        for (int k = 0; k < KSZ; ++k)
            w[c][k] = __int_as_float(
                __builtin_amdgcn_readfirstlane(__float_as_int(cw[c * KSZ + k])));
    const float bias = __int_as_float(
        __builtin_amdgcn_readfirstlane(__float_as_int(cb[0])));

    int goff[NLD], loff[NLD];
#pragma unroll
    for (int u = 0; u < NLD; ++u) {
        int g4  = lane + 64 * u;
        int row = g4 / NLD;
        int c4  = g4 - row * NLD;
        goff[u] = row * XROW + 4 * c4;
        loff[u] = row * TW + 4 * c4;
    }
    const float* xw = x + (size_t)g * 64 * XROW + tbase;

    float acc[NS];
#pragma unroll
    for (int i = 0; i < NS; ++i) acc[i] = bias;

    float4 buf[NLD];
#pragma unroll
    for (int u = 0; u < NLD; ++u) buf[u] = *(const float4*)(xw + goff[u]);

#pragma unroll
    for (int ch = 0; ch < CIN; ++ch) {
#pragma unroll
        for (int u = 0; u < NLD; ++u) {
            float* dst = tile + loff[u];
            dst[0] = buf[u].x; dst[1] = buf[u].y; dst[2] = buf[u].z; dst[3] = buf[u].w;
        }
        if (ch + 1 < CIN) {
#pragma unroll
            for (int u = 0; u < NLD; ++u)
                buf[u] = *(const float4*)(xw + (ch + 1) * LW + goff[u]);
        }
        const float* row = tile + lane * TW + off;
        float x0 = row[0], x1 = row[1], x2 = row[2], x3 = row[3];
#pragma unroll
        for (int i = 0; i < NS; ++i) {
            float x4v = row[i + 4];
            float a = acc[i];
            a = fmaf(x0, w[ch][0], a);
            a = fmaf(x1, w[ch][1], a);
            a = fmaf(x2, w[ch][2], a);
            a = fmaf(x3, w[ch][3], a);
            a = fmaf(x4v, w[ch][4], a);
            acc[i] = a;
            x0 = x1; x1 = x2; x2 = x3; x3 = x4v;
        }
    }

    float* pb = part + (size_t)(s * NH1) * BATCH + (size_t)g * 64 + lane;
#pragma unroll
    for (int half = 0; half < 2; ++half) {
        const int j0 = half * 25;
        float h1p[25];
#pragma unroll
        for (int j = 0; j < 25; ++j) h1p[j] = 0.f;
#pragma unroll
        for (int ii = 0; ii < NS; ++ii) {
            const float* wrow = w1 + (size_t)(kstart + ii) * NH1 + j0;
            float c = acc[ii];
#pragma unroll
            for (int j = 0; j < 25; ++j) h1p[j] = fmaf(c, wrow[j], h1p[j]);
        }
#pragma unroll
        for (int j = 0; j < 25; ++j)
            pb[(size_t)(j0 + j) * BATCH] = h1p[j];
    }
}

__global__ void __launch_bounds__(64)
conv_fc1_k4(const float* __restrict__ x,
            const float* __restrict__ cw, const float* __restrict__ cb,
            const float* __restrict__ w1, float* __restrict__ part)
{
    __shared__ float tile[64 * 57];
    conv_fc1_body<49, 48, 14, 57, 4>(x, cw, cb, w1, part, tile);
}

__global__ void __launch_bounds__(64)
conv_fc1_k2(const float* __restrict__ x,
            const float* __restrict__ cw, const float* __restrict__ cb,
            const float* __restrict__ w1, float* __restrict__ part)
{
    __shared__ float tile[64 * 105];
    conv_fc1_body<98, 96, 26, 105, 2>(x, cw, cb, w1, part, tile);
}

// ---------------- K2: fused reduce+fc2, fc3, Procrustes ----------------
template<int NSPLIT>
__global__ void __launch_bounds__(64)
tail_kernel(
    const float* __restrict__ part,
    const float* __restrict__ b1,
    const float* __restrict__ w2, const float* __restrict__ b2,
    const float* __restrict__ w3, const float* __restrict__ b3,
    float* __restrict__ out)
{
    const int bid = blockIdx.x;
    const int g   = (bid & 7) * 64 + (bid >> 3);   // same XCD chunking as K1
    const int b   = g * 64 + threadIdx.x;
    const float* pb = part + b;

    float h2[NH2];
#pragma unroll
    for (int j = 0; j < NH2; ++j) h2[j] = b2[j];

#pragma unroll
    for (int k = 0; k < NH1; ++k) {
        float a = b1[k];                           // uniform -> s_load
#pragma unroll
        for (int s = 0; s < NSPLIT; ++s)
            a += pb[(size_t)(s * NH1 + k) * BATCH];
        float hk = fmaxf(a, 0.f);
        const float* row = w2 + k * NH2;           // uniform -> s_load
#pragma unroll
        for (int j = 0; j < NH2; ++j) h2[j] = fmaf(hk, row[j], h2[j]);
    }
#pragma unroll
    for (int j = 0; j < NH2; ++j) h2[j] = fmaxf(h2[j], 0.f);

    // fc3 (no relu)
    float o[NOUT];
#pragma unroll
    for (int j = 0; j < NOUT; ++j) o[j] = b3[j];
#pragma unroll
    for (int k = 0; k < NH2; ++k) {
        float hk = h2[k];
        const float* row = w3 + k * NOUT;          // uniform -> s_load
#pragma unroll
        for (int j = 0; j < NOUT; ++j) o[j] = fmaf(hk, row[j], o[j]);
    }

    // ---- closest proper rotation (Davenport K-matrix, f32 Jacobi) ----
    float r00 = o[0], r01 = o[1], r02 = o[2];
    float r10 = o[3], r11 = o[4], r12 = o[5];
    float r20 = o[6], r21 = o[7], r22 = o[8];

    float A[4][4], V[4][4];
    A[0][0] = r00 + r11 + r22;
    A[1][1] = r00 - r11 - r22;
    A[2][2] = r11 - r00 - r22;
    A[3][3] = r22 - r00 - r11;
    A[0][1] = A[1][0] = r21 - r12;
    A[0][2] = A[2][0] = r02 - r20;
    A[0][3] = A[3][0] = r10 - r01;
    A[1][2] = A[2][1] = r01 + r10;
    A[1][3] = A[3][1] = r02 + r20;
    A[2][3] = A[3][2] = r12 + r21;
#pragma unroll
    for (int i = 0; i < 4; ++i)
#pragma unroll
        for (int j = 0; j < 4; ++j) V[i][j] = (i == j) ? 1.f : 0.f;

    const int pr[6][2] = {{0,1},{0,2},{0,3},{1,2},{1,3},{2,3}};
    for (int sweep = 0; sweep < 7; ++sweep) {
#pragma unroll
        for (int pi = 0; pi < 6; ++pi) {
            const int p = pr[pi][0], qq = pr[pi][1];
            float apq = A[p][qq];
            if (fabsf(apq) > 1e-20f) {
                float theta = (A[qq][qq] - A[p][p]) / (2.f * apq);
                float t = copysignf(1.f, theta) / (fabsf(theta) + sqrtf(1.f + theta * theta));
                float c = rsqrtf(1.f + t * t);
                float sn = t * c;
#pragma unroll
                for (int k = 0; k < 4; ++k) {
                    float akp = A[k][p], akq = A[k][qq];
                    A[k][p] = c * akp - sn * akq;
                    A[k][qq] = sn * akp + c * akq;
                }
#pragma unroll
                for (int k = 0; k < 4; ++k) {
                    float apk = A[p][k], aqk = A[qq][k];
                    A[p][k] = c * apk - sn * aqk;
                    A[qq][k] = sn * apk + c * aqk;
                }
#pragma unroll
                for (int k = 0; k < 4; ++k) {
                    float vkp = V[k][p], vkq = V[k][qq];
                    V[k][p] = c * vkp - sn * vkq;
                    V[k][qq] = sn * vkp + c * vkq;
                }
            }
        }
    }

    int best = 0;
    float bl = A[0][0];
#pragma unroll
    for (int i = 1; i < 4; ++i)
        if (A[i][i] > bl) { bl = A[i][i]; best = i; }

    // static-index column select (dynamic V[k][best] risks scratch demotion)
    float vsel[4];
#pragma unroll
    for (int k = 0; k < 4; ++k) {
        float v = V[k][0];
        v = (best == 1) ? V[k][1] : v;
        v = (best == 2) ? V[k][2] : v;
        v = (best == 3) ? V[k][3] : v;
        vsel[k] = v;
    }
    float vw = vsel[0], vx = vsel[1], vy = vsel[2], vz = vsel[3];
    float inv = rsqrtf(vw * vw + vx * vx + vy * vy + vz * vz);
    vw *= inv; vx *= inv; vy *= inv; vz *= inv;

    float xx = vx * vx, yy = vy * vy, zz = vz * vz;
    float xy = vx * vy, xz = vx * vz, yz = vy * vz;
    float wx = vw * vx, wy = vw * vy, wz = vw * vz;

    float* ob = out + (long)b * NOUT;
    ob[0]  = 1.f - 2.f * (yy + zz);
    ob[1]  = 2.f * (xy - wz);
    ob[2]  = 2.f * (xz + wy);
    ob[3]  = 2.f * (xy + wz);
    ob[4]  = 1.f - 2.f * (xx + zz);
    ob[5]  = 2.f * (yz - wx);
    ob[6]  = 2.f * (xz - wy);
    ob[7]  = 2.f * (yz + wx);
    ob[8]  = 1.f - 2.f * (xx + yy);
    ob[9]  = o[9];
    ob[10] = o[10];
    ob[11] = o[11];
    ob[12] = o[12];
    ob[13] = o[13];
    ob[14] = o[14];
}

extern "C" void kernel_launch(void* const* d_in, const int* in_sizes, int n_in,
                              void* d_out, int out_size, void* d_ws, size_t ws_size,
                              hipStream_t stream) {
    const float* x  = (const float*)d_in[0];
    const float* cw = (const float*)d_in[1];
    const float* cb = (const float*)d_in[2];
    const float* w1 = (const float*)d_in[3];
    const float* b1 = (const float*)d_in[4];
    const float* w2 = (const float*)d_in[5];
    const float* b2 = (const float*)d_in[6];
    const float* w3 = (const float*)d_in[7];
    const float* b3 = (const float*)d_in[8];
    float* outp = (float*)d_out;
    float* part = (float*)d_ws;

    const size_t need7 = (size_t)7 * NH1 * BATCH * sizeof(float);  // 45.9 MB
    const size_t need4 = (size_t)4 * NH1 * BATCH * sizeof(float);  // 26.2 MB

    if (ws_size >= need7) {
        conv_fc1_k7<<<7 * (BATCH / 64), 64, 0, stream>>>(x, cw, cb, w1, part);
        tail_kernel<7><<<BATCH / 64, 64, 0, stream>>>(part, b1, w2, b2, w3, b3, outp);
    } else if (ws_size >= need4) {
        conv_fc1_k4<<<4 * (BATCH / 64), 64, 0, stream>>>(x, cw, cb, w1, part);
        tail_kernel<4><<<BATCH / 64, 64, 0, stream>>>(part, b1, w2, b2, w3, b3, outp);
    } else {
        conv_fc1_k2<<<2 * (BATCH / 64), 64, 0, stream>>>(x, cw, cb, w1, part);
        tail_kernel<2><<<BATCH / 64, 64, 0, stream>>>(part, b1, w2, b2, w3, b3, outp);
    }
}